// Round 4
// baseline (381.623 us; speedup 1.0000x reference)
//
#include <hip/hip_runtime.h>
#include <hip/hip_bf16.h>

// ---------------------------------------------------------------------------
// GAT 2-layer forward on MI355X (gfx950).
// R3: (a) wave-per-dst aggregation (no barriers, wave-private LDS weights,
//         shfl src broadcast) -> more MLP, less fixed overhead;
//     (b) GEMM1 tile 128x256 -> A staged once;
//     (c) count/scatter vectorized x4.
// fp16 intermediates, MFMA f16 GEMMs, softmax shift-invariance (no max pass),
// end-normalization (no separate denom pass).
// ---------------------------------------------------------------------------

typedef _Float16 half8v __attribute__((ext_vector_type(8)));
typedef _Float16 half4v __attribute__((ext_vector_type(4)));
typedef _Float16 half2v __attribute__((ext_vector_type(2)));
typedef float f32x4 __attribute__((ext_vector_type(4)));

// --- MFMA GEMM1: C[M,256](f16) = A[M,256](f32) @ B[256,256]^T(f32) ---------
// 128x256 tile, BK=32, 512 threads = 8 waves (2x4), each wave 64x64.

__global__ __launch_bounds__(512) void gemm1_kernel(
    const float* __restrict__ A,   // [M,K] f32
    const float* __restrict__ B,   // [N,K] f32 weights
    _Float16* __restrict__ C,      // [M,N] f16
    int M, int N, int K)
{
    constexpr int BM = 128, BN = 256, BK = 32, LDA = 40;
    __shared__ _Float16 Ah[BM * LDA];
    __shared__ _Float16 Bh[BN * LDA];

    const int tid = threadIdx.x;
    const int m0 = blockIdx.x * BM;
    const int w  = tid >> 6;
    const int l  = tid & 63;
    const int wm = (w >> 2) * 64;
    const int wn = (w & 3) * 64;
    const int lr = l & 15;
    const int lq = l >> 4;

    f32x4 acc[4][4] = {};

    for (int k0 = 0; k0 < K; k0 += BK) {
        // stage A (128x32 f32 -> f16): 2 float4 per thread
#pragma unroll
        for (int it = 0; it < 2; ++it) {
            const int row = (tid >> 3) + it * 64;
            const int gm  = min(m0 + row, M - 1);
            const int c4  = (tid & 7) * 4;
            float4 v = *reinterpret_cast<const float4*>(A + (long)gm * K + k0 + c4);
            half4v o = { (_Float16)v.x, (_Float16)v.y, (_Float16)v.z, (_Float16)v.w };
            *reinterpret_cast<half4v*>(&Ah[row * LDA + c4]) = o;
        }
        // stage B (256x32 f32 -> f16): 4 float4 per thread
#pragma unroll
        for (int it = 0; it < 4; ++it) {
            const int row = (tid >> 3) + it * 64;
            const int c4  = (tid & 7) * 4;
            float4 v = *reinterpret_cast<const float4*>(B + (long)row * K + k0 + c4);
            half4v o = { (_Float16)v.x, (_Float16)v.y, (_Float16)v.z, (_Float16)v.w };
            *reinterpret_cast<half4v*>(&Bh[row * LDA + c4]) = o;
        }
        __syncthreads();

        half8v af[4], bf[4];
#pragma unroll
        for (int i = 0; i < 4; ++i)
            af[i] = *reinterpret_cast<const half8v*>(&Ah[(wm + i * 16 + lr) * LDA + lq * 8]);
#pragma unroll
        for (int j = 0; j < 4; ++j)
            bf[j] = *reinterpret_cast<const half8v*>(&Bh[(wn + j * 16 + lr) * LDA + lq * 8]);
#pragma unroll
        for (int i = 0; i < 4; ++i)
#pragma unroll
            for (int j = 0; j < 4; ++j)
                acc[i][j] = __builtin_amdgcn_mfma_f32_16x16x32_f16(af[i], bf[j], acc[i][j], 0, 0, 0);
        __syncthreads();
    }

#pragma unroll
    for (int i = 0; i < 4; ++i) {
        const int gm_base = m0 + wm + i * 16 + lq * 4;
#pragma unroll
        for (int r = 0; r < 4; ++r) {
            const int gm = gm_base + r;
            if (gm < M) {
#pragma unroll
                for (int j = 0; j < 4; ++j)
                    C[(long)gm * N + wn + j * 16 + lr] = (_Float16)acc[i][j][r];
            }
        }
    }
}

// --- MFMA GEMM2: C[M,128](f16) = A[M,256](f16) @ B[128,256]^T(f32) ---------
// 128x128 tile, BK=32, 256 threads = 4 waves (2x2).

__global__ __launch_bounds__(256) void gemm2_kernel(
    const _Float16* __restrict__ A,  // [M,K] f16
    const float* __restrict__ B,     // [N,K] f32 weights
    _Float16* __restrict__ C,        // [M,N] f16
    int M, int N, int K)
{
    constexpr int BM = 128, BK = 32, LDA = 40;
    __shared__ _Float16 Ah[BM * LDA];
    __shared__ _Float16 Bh[BM * LDA];

    const int tid = threadIdx.x;
    const int m0 = blockIdx.x * BM;
    const int w  = tid >> 6;
    const int l  = tid & 63;
    const int wm = (w >> 1) * 64;
    const int wn = (w & 1) * 64;
    const int lr = l & 15;
    const int lq = l >> 4;

    f32x4 acc[4][4] = {};

    for (int k0 = 0; k0 < K; k0 += BK) {
#pragma unroll
        for (int it = 0; it < 2; ++it) {
            const int row = (tid >> 2) + it * 64;
            const int gm  = min(m0 + row, M - 1);
            const int c8  = (tid & 3) * 8;
            float4 v = *reinterpret_cast<const float4*>((const char*)A + ((long)gm * K + k0 + c8) * 2);
            *reinterpret_cast<float4*>(&Ah[row * LDA + c8]) = v;
        }
#pragma unroll
        for (int it = 0; it < 4; ++it) {
            const int row = (tid >> 3) + it * 32;
            const int c4  = (tid & 7) * 4;
            float4 v = *reinterpret_cast<const float4*>(B + (long)row * K + k0 + c4);
            half4v o = { (_Float16)v.x, (_Float16)v.y, (_Float16)v.z, (_Float16)v.w };
            *reinterpret_cast<half4v*>(&Bh[row * LDA + c4]) = o;
        }
        __syncthreads();

        half8v af[4], bf[4];
#pragma unroll
        for (int i = 0; i < 4; ++i)
            af[i] = *reinterpret_cast<const half8v*>(&Ah[(wm + i * 16 + lr) * LDA + lq * 8]);
#pragma unroll
        for (int j = 0; j < 4; ++j)
            bf[j] = *reinterpret_cast<const half8v*>(&Bh[(wn + j * 16 + lr) * LDA + lq * 8]);
#pragma unroll
        for (int i = 0; i < 4; ++i)
#pragma unroll
            for (int j = 0; j < 4; ++j)
                acc[i][j] = __builtin_amdgcn_mfma_f32_16x16x32_f16(af[i], bf[j], acc[i][j], 0, 0, 0);
        __syncthreads();
    }

#pragma unroll
    for (int i = 0; i < 4; ++i) {
        const int gm_base = m0 + wm + i * 16 + lq * 4;
#pragma unroll
        for (int r = 0; r < 4; ++r) {
            const int gm = gm_base + r;
            if (gm < M) {
#pragma unroll
                for (int j = 0; j < 4; ++j)
                    C[(long)gm * N + wn + j * 16 + lr] = (_Float16)acc[i][j][r];
            }
        }
    }
}

// --- CSR build --------------------------------------------------------------

__global__ void count_kernel(const int* __restrict__ dst, int* __restrict__ deg, int E)
{
    const int e4 = (blockIdx.x * blockDim.x + threadIdx.x) * 4;
    if (e4 + 3 < E) {
        const int4 d = *reinterpret_cast<const int4*>(dst + e4);
        atomicAdd(&deg[d.x], 1);
        atomicAdd(&deg[d.y], 1);
        atomicAdd(&deg[d.z], 1);
        atomicAdd(&deg[d.w], 1);
    } else {
        for (int k = e4; k < E; ++k) atomicAdd(&deg[dst[k]], 1);
    }
}

__global__ __launch_bounds__(256) void block_scan_kernel(
    const int* __restrict__ deg, int* __restrict__ pre, int* __restrict__ blk, int n)
{
    __shared__ int s[256];
    const int t = threadIdx.x;
    const int base = blockIdx.x * 1024 + t * 4;
    int4 d = make_int4(-1, -1, -1, -1);
    if (base + 3 < n) d = *reinterpret_cast<const int4*>(deg + base);
    else {
        if (base + 0 < n) d.x = deg[base + 0];
        if (base + 1 < n) d.y = deg[base + 1];
        if (base + 2 < n) d.z = deg[base + 2];
        if (base + 3 < n) d.w = deg[base + 3];
    }
    const int v0 = d.x + 1, v1 = d.y + 1, v2 = d.z + 1, v3 = d.w + 1;
    s[t] = v0 + v1 + v2 + v3;
    __syncthreads();
#pragma unroll
    for (int o = 1; o < 256; o <<= 1) {
        int val = 0;
        if (t >= o) val = s[t - o];
        __syncthreads();
        s[t] += val;
        __syncthreads();
    }
    int run = (t == 0) ? 0 : s[t - 1];
    int4 o4;
    o4.x = run; run += v0;
    o4.y = run; run += v1;
    o4.z = run; run += v2;
    o4.w = run; run += v3;
    if (base + 3 < n) *reinterpret_cast<int4*>(pre + base) = o4;
    else {
        if (base + 0 < n) pre[base + 0] = o4.x;
        if (base + 1 < n) pre[base + 1] = o4.y;
        if (base + 2 < n) pre[base + 2] = o4.z;
        if (base + 3 < n) pre[base + 3] = o4.w;
    }
    if (t == 255) blk[blockIdx.x] = s[255];
}

__global__ void total_scan_kernel(const int* __restrict__ blk, int* __restrict__ blk_off,
                                  int* __restrict__ off_end, int nb)
{
    const int l = threadIdx.x;
    const int self = (l < nb) ? blk[l] : 0;
    int v = self;
#pragma unroll
    for (int o = 1; o < 64; o <<= 1) {
        int u = __shfl_up(v, o, 64);
        if (l >= o) v += u;
    }
    if (l < nb) blk_off[l] = v - self;
    if (l == nb - 1) *off_end = v;
}

__global__ __launch_bounds__(256) void finalize_scan_kernel(
    const int* __restrict__ pre, const int* __restrict__ blk_off,
    int* __restrict__ off, int* __restrict__ cursor, int n)
{
    const int t = threadIdx.x;
    const int base = blockIdx.x * 1024 + t * 4;
    const int add = blk_off[blockIdx.x];
    if (base + 3 < n) {
        int4 p = *reinterpret_cast<const int4*>(pre + base);
        p.x += add; p.y += add; p.z += add; p.w += add;
        *reinterpret_cast<int4*>(off + base) = p;
        *reinterpret_cast<int4*>(cursor + base) = p;
    } else {
#pragma unroll
        for (int k = 0; k < 4; ++k)
            if (base + k < n) {
                const int v = pre[base + k] + add;
                off[base + k] = v;
                cursor[base + k] = v;
            }
    }
}

__global__ void scatter_kernel(const int* __restrict__ src, const int* __restrict__ dst,
                               int* __restrict__ cursor, int* __restrict__ csr_src,
                               int E, int N)
{
    const int e4 = (blockIdx.x * blockDim.x + threadIdx.x) * 4;
    if (e4 + 3 < E) {
        const int4 s = *reinterpret_cast<const int4*>(src + e4);
        const int4 d = *reinterpret_cast<const int4*>(dst + e4);
        csr_src[atomicAdd(&cursor[d.x], 1)] = s.x;
        csr_src[atomicAdd(&cursor[d.y], 1)] = s.y;
        csr_src[atomicAdd(&cursor[d.z], 1)] = s.z;
        csr_src[atomicAdd(&cursor[d.w], 1)] = s.w;
    } else if (e4 < E) {
        for (int k = e4; k < E; ++k)
            csr_src[atomicAdd(&cursor[dst[k]], 1)] = src[k];
    } else {
        const int nn = (e4 - E) / 4 * 4 + (0);
        // handled below by dedicated range
    }
    // self loops: map extra threads past ceil(E/4)
    const int tid = blockIdx.x * blockDim.x + threadIdx.x;
    const int eBlocks = (E + 3) / 4;
    const int nn = tid - eBlocks;
    if (nn >= 0 && nn < N)
        csr_src[atomicAdd(&cursor[nn], 1)] = nn;
}

// --- attention logits: a[n,h] = sum_c h[n,h,c]*att[h,c], C=128, fp16 h ------

template <int H>
__global__ __launch_bounds__(256) void att_kernel(
    const _Float16* __restrict__ h,
    const float* __restrict__ att_s,
    const float* __restrict__ att_d,
    float* __restrict__ a_s,
    float* __restrict__ a_d,
    int N)
{
    const int g = (blockIdx.x * 256 + threadIdx.x) >> 6;
    const int l = threadIdx.x & 63;
    if (g >= N * H) return;
    const int n  = g / H;
    const int hh = g % H;
    const _Float16* row = h + (long)n * (H * 128) + hh * 128;
    const float* asv = att_s + hh * 128;
    const float* adv = att_d + hh * 128;
    const float v0 = (float)row[l], v1 = (float)row[l + 64];
    float ss = v0 * asv[l] + v1 * asv[l + 64];
    float dd = v0 * adv[l] + v1 * adv[l + 64];
#pragma unroll
    for (int o = 32; o > 0; o >>= 1) {
        ss += __shfl_xor(ss, o, 64);
        dd += __shfl_xor(dd, o, 64);
    }
    if (l == 0) { a_s[g] = ss; a_d[g] = dd; }
}

// --- wave-per-dst aggregation (fp16 messages, fp32 accumulate) -------------
// One 64-lane wave per destination; weights staged in a wave-private LDS
// slice (in-wave ds ordering -> NO barriers); src indices via __shfl.
// out[d,c] = (sum_e w * h[s_e,c]) / (sum_e w) [+bias][relu]

template <int H, int C, int VPT, bool RELU, typename TOUT>
__global__ __launch_bounds__(256) void aggregate_kernel(
    const int* __restrict__ csr_off,
    const int* __restrict__ csr_src,
    const _Float16* __restrict__ h,  // [N, H*C] fp16
    const float* __restrict__ a_s,   // [N, H]
    const float* __restrict__ a_d,   // [N, H]
    const float* __restrict__ bias,  // [H*C]
    TOUT* __restrict__ out,          // [N, H*C]
    int N)
{
    const int wave = threadIdx.x >> 6;
    const int l    = threadIdx.x & 63;
    const int col  = l * VPT;              // 64*VPT == H*C
    const int hh   = col / C;
    const int d    = blockIdx.x * 4 + wave;

    __shared__ float s_w[4][64][H];

    if (d >= N) return;

    const int beg = csr_off[d];
    const int end = csr_off[d + 1];

    float ad_loc[H];
#pragma unroll
    for (int h2 = 0; h2 < H; ++h2) ad_loc[h2] = a_d[d * H + h2];

    float acc[VPT] = {};
    float wsum = 0.f;

    for (int base = beg; base < end; base += 64) {
        const int len = min(64, end - base);
        int s = 0;
        if (l < len) {
            s = csr_src[base + l];
#pragma unroll
            for (int h2 = 0; h2 < H; ++h2) {
                float logit = a_s[s * H + h2] + ad_loc[h2];
                logit = logit > 0.f ? logit : 0.2f * logit;
                s_w[wave][l][h2] = __expf(logit);
            }
        }
        // wave-private LDS: no __syncthreads needed (in-wave lgkmcnt ordering)
#pragma unroll 4
        for (int j = 0; j < len; ++j) {
            const int   sj = __shfl(s, j, 64);
            const float w  = s_w[wave][j][hh];
            if constexpr (VPT == 4) {
                half4v hv = *reinterpret_cast<const half4v*>(h + (long)sj * (H * C) + col);
                acc[0] += w * (float)hv.x;
                acc[1] += w * (float)hv.y;
                acc[2] += w * (float)hv.z;
                acc[3] += w * (float)hv.w;
            } else {
                half2v hv = *reinterpret_cast<const half2v*>(h + (long)sj * (H * C) + col);
                acc[0] += w * (float)hv.x;
                acc[1] += w * (float)hv.y;
            }
            wsum += w;
        }
    }

    const float inv = 1.f / wsum;
    if constexpr (__is_same(TOUT, _Float16)) {
        _Float16 o[VPT];
#pragma unroll
        for (int k = 0; k < VPT; ++k) {
            float r = acc[k] * inv + bias[col + k];
            if (RELU) r = r > 0.f ? r : 0.f;
            o[k] = (_Float16)r;
        }
        if constexpr (VPT == 4)
            *reinterpret_cast<half4v*>(out + (long)d * (H * C) + col) =
                half4v{o[0], o[1], o[2], o[3]};
        else
            *reinterpret_cast<half2v*>(out + (long)d * (H * C) + col) =
                half2v{o[0], o[1]};
    } else {
        float r[VPT];
#pragma unroll
        for (int k = 0; k < VPT; ++k) {
            r[k] = acc[k] * inv + bias[col + k];
            if (RELU) r[k] = r[k] > 0.f ? r[k] : 0.f;
        }
        if constexpr (VPT == 2)
            *reinterpret_cast<float2*>(out + (long)d * (H * C) + col) = make_float2(r[0], r[1]);
        else
#pragma unroll
            for (int k = 0; k < VPT; ++k) out[(long)d * (H * C) + col + k] = r[k];
    }
}

// ---------------------------------------------------------------------------

extern "C" void kernel_launch(void* const* d_in, const int* in_sizes, int n_in,
                              void* d_out, int out_size, void* d_ws, size_t ws_size,
                              hipStream_t stream)
{
    const float* x    = (const float*)d_in[0];
    const int*   eidx = (const int*)d_in[1];
    const float* W1   = (const float*)d_in[2];
    const float* as1  = (const float*)d_in[3];
    const float* ad1  = (const float*)d_in[4];
    const float* b1   = (const float*)d_in[5];
    const float* W2   = (const float*)d_in[6];
    const float* as2  = (const float*)d_in[7];
    const float* ad2  = (const float*)d_in[8];
    const float* b2   = (const float*)d_in[9];
    float* out = (float*)d_out;

    const int IN_FEATS = 256;
    const int N = in_sizes[0] / IN_FEATS;    // 50000
    const int E = in_sizes[1] / 2;           // 800000

    const int* esrc = eidx;
    const int* edst = eidx + E;

    size_t off = 0;
    auto alloc = [&](size_t bytes) -> void* {
        void* p = (char*)d_ws + off;
        off += (bytes + 255) & ~(size_t)255;
        return p;
    };
    _Float16* h1h   = (_Float16*)alloc((size_t)N * 256 * 2);
    _Float16* o1h   = (_Float16*)alloc((size_t)N * 256 * 2);
    _Float16* h2h   = (_Float16*)alloc((size_t)N * 128 * 2);
    float* a1s      = (float*)alloc((size_t)N * 2 * 4);
    float* a1d      = (float*)alloc((size_t)N * 2 * 4);
    float* a2s      = (float*)alloc((size_t)N * 4);
    float* a2d      = (float*)alloc((size_t)N * 4);
    int*   deg      = (int*)alloc((size_t)N * 4);
    int*   pre      = (int*)alloc((size_t)N * 4);
    int*   cursor   = (int*)alloc((size_t)N * 4);
    int*   csr_off  = (int*)alloc((size_t)(N + 1) * 4);
    int*   csr_src  = (int*)alloc((size_t)(E + N) * 4);
    int*   blk      = (int*)alloc(64 * 4);
    int*   blk_off  = (int*)alloc(64 * 4);

    const int nbScan = (N + 1023) / 1024;    // 49 <= 64

    // --- CSR build (same graph both layers) ---
    hipMemsetAsync(deg, 0, (size_t)N * 4, stream);
    count_kernel<<<(E / 4 + 255) / 256, 256, 0, stream>>>(edst, deg, E);
    block_scan_kernel<<<nbScan, 256, 0, stream>>>(deg, pre, blk, N);
    total_scan_kernel<<<1, 64, 0, stream>>>(blk, blk_off, csr_off + N, nbScan);
    finalize_scan_kernel<<<nbScan, 256, 0, stream>>>(pre, blk_off, csr_off, cursor, N);
    {
        const int eThreads = (E + 3) / 4 + N;   // edge quads + self loops
        scatter_kernel<<<(eThreads + 255) / 256, 256, 0, stream>>>(
            esrc, edst, cursor, csr_src, E, N);
    }

    // --- layer 1 ---
    gemm1_kernel<<<(N + 127) / 128, 512, 0, stream>>>(x, W1, h1h, N, 256, 256);
    att_kernel<2><<<(N * 2 + 3) / 4, 256, 0, stream>>>(h1h, as1, ad1, a1s, a1d, N);
    aggregate_kernel<2, 128, 4, true, _Float16><<<(N + 3) / 4, 256, 0, stream>>>(
        csr_off, csr_src, h1h, a1s, a1d, b1, o1h, N);

    // --- layer 2 ---
    gemm2_kernel<<<(N + 127) / 128, 256, 0, stream>>>(o1h, W2, h2h, N, 128, 256);
    att_kernel<1><<<(N + 3) / 4, 256, 0, stream>>>(h2h, as2, ad2, a2s, a2d, N);
    aggregate_kernel<1, 128, 2, false, float><<<(N + 3) / 4, 256, 0, stream>>>(
        csr_off, csr_src, h2h, a2s, a2d, b2, out, N);
}